// Round 1
// baseline (417.409 us; speedup 1.0000x reference)
//
#include <hip/hip_runtime.h>
#include <hip/hip_bf16.h>

#define NT   4096
#define NH   12
#define INS  256
#define DOUT 128
#define D1   129

typedef __attribute__((ext_vector_type(8))) short bf16x8;
typedef __attribute__((ext_vector_type(4))) float f32x4;

__device__ __forceinline__ short f2bf(float f) {
  union { __hip_bfloat16 h; short s; } u;
  u.h = __float2bfloat16(f);
  return u.s;
}
__device__ __forceinline__ float bf2f(short s) {
  union { unsigned u; float f; } v;
  v.u = ((unsigned)(unsigned short)s) << 16;
  return v.f;
}

#define MFMA16(a,b,c) __builtin_amdgcn_mfma_f32_16x16x32_bf16((a),(b),(c),0,0,0)

#define GL2LDS(gp, lp) \
  __builtin_amdgcn_global_load_lds((const __attribute__((address_space(1))) unsigned*)(gp), \
                                   (__attribute__((address_space(3))) unsigned*)(lp), 16, 0, 0)

// ---------------- conversion kernels ----------------

__global__ void k_cvt_xs(const float* __restrict__ xl, short* __restrict__ xs) {
  int i = blockIdx.x * 256 + threadIdx.x;       // 0 .. NT*INS-1
  int row = i >> 8, col = i & 255;
  xs[i] = f2bf(xl[row * 257 + 1 + col]);
}

__global__ void k_cvt_w(const float* __restrict__ w0, const float* __restrict__ w1,
                        const float* __restrict__ w2, short* __restrict__ dst) {
  int i = blockIdx.x * 256 + threadIdx.x;       // 0 .. NH*DOUT*INS-1
  const float* s = blockIdx.y == 0 ? w0 : (blockIdx.y == 1 ? w1 : w2);
  dst[(size_t)blockIdx.y * (NH * DOUT * INS) + i] = f2bf(s[i]);
}

// ---------------- projection: s = xs@W^T + b ; t = sqrt(|s|^2+1) ----------------
// grid (NT/128, NH, 3), block 256 (4 waves, each 32 rows x 128 cols)

__launch_bounds__(256, 2)
__global__ void k_proj(const short* __restrict__ xs, const short* __restrict__ Wb,
                       const float* __restrict__ b0, const float* __restrict__ b1,
                       const float* __restrict__ b2,
                       short* __restrict__ Qb, short* __restrict__ Kb, short* __restrict__ VT,
                       float* __restrict__ qt, float* __restrict__ kt, float* __restrict__ vt) {
  __shared__ __align__(16) short vlds[128][144];   // V transpose staging (d, n_local), pad 16 shorts->stride 288B
  int t = threadIdx.x, l = t & 63, w = t >> 6;
  int lr = l & 15, lg = l >> 4;
  int h = blockIdx.y, z = blockIdx.z;
  int n0w = blockIdx.x * 128 + w * 32;
  const short* Wh = Wb + ((size_t)z * NH + h) * DOUT * INS;
  const float* bias = z == 0 ? b0 : (z == 1 ? b1 : b2);

  f32x4 acc[2][8] = {};
#pragma unroll
  for (int dk = 0; dk < 8; ++dk) {
    bf16x8 a[2], b[8];
#pragma unroll
    for (int qf = 0; qf < 2; ++qf)
      a[qf] = *(const bf16x8*)(xs + (size_t)(n0w + 16 * qf + lr) * INS + dk * 32 + lg * 8);
#pragma unroll
    for (int cf = 0; cf < 8; ++cf)
      b[cf] = *(const bf16x8*)(Wh + (size_t)(lr + 16 * cf) * INS + dk * 32 + lg * 8);
#pragma unroll
    for (int qf = 0; qf < 2; ++qf)
#pragma unroll
      for (int cf = 0; cf < 8; ++cf)
        acc[qf][cf] = MFMA16(a[qf], b[cf], acc[qf][cf]);
  }

  float tval[2][4];
#pragma unroll
  for (int qf = 0; qf < 2; ++qf) {
    float ssq[4] = {0.f, 0.f, 0.f, 0.f};
#pragma unroll
    for (int cf = 0; cf < 8; ++cf) {
      float bv = bias[h * DOUT + lr + 16 * cf];
#pragma unroll
      for (int r = 0; r < 4; ++r) {
        acc[qf][cf][r] += bv;
        ssq[r] += acc[qf][cf][r] * acc[qf][cf][r];
      }
    }
#pragma unroll
    for (int r = 0; r < 4; ++r) {
      float s = ssq[r];
      s += __shfl_xor(s, 1); s += __shfl_xor(s, 2);
      s += __shfl_xor(s, 4); s += __shfl_xor(s, 8);
      tval[qf][r] = sqrtf(s + 1.0f);
    }
  }

  if (z < 2) {
    short* Ob = (z == 0) ? Qb : Kb;
    float* Ot = (z == 0) ? qt : kt;
#pragma unroll
    for (int qf = 0; qf < 2; ++qf)
#pragma unroll
      for (int r = 0; r < 4; ++r) {
        int n = n0w + 16 * qf + lg * 4 + r;
#pragma unroll
        for (int cf = 0; cf < 8; ++cf)
          Ob[((size_t)h * NT + n) * DOUT + lr + 16 * cf] = f2bf(acc[qf][cf][r]);
        if (lr == 0) Ot[(size_t)h * NT + n] = tval[qf][r];
      }
  } else {
    // V: write transposed (H, DOUT, NT) via LDS for coalescing
#pragma unroll
    for (int qf = 0; qf < 2; ++qf)
#pragma unroll
      for (int cf = 0; cf < 8; ++cf)
#pragma unroll
        for (int r = 0; r < 4; ++r) {
          int nl = w * 32 + 16 * qf + lg * 4 + r;
          vlds[lr + 16 * cf][nl] = f2bf(acc[qf][cf][r]);
        }
#pragma unroll
    for (int qf = 0; qf < 2; ++qf)
#pragma unroll
      for (int r = 0; r < 4; ++r) {
        int n = n0w + 16 * qf + lg * 4 + r;
        if (lr == 0) vt[(size_t)h * NT + n] = tval[qf][r];
      }
    __syncthreads();
    int d = t >> 1, half = t & 1;
    const short* src = &vlds[d][half * 64];
    short* dst = VT + ((size_t)h * DOUT + d) * NT + blockIdx.x * 128 + half * 64;
#pragma unroll
    for (int j = 0; j < 8; ++j)
      *(bf16x8*)(dst + j * 8) = *(const bf16x8*)(src + j * 8);
  }
}

// ---------------- flash attention + first midpoint-norm + head accumulation ----------------
// grid (NT/128, NH), block 256. Wave w owns q-rows [blk*128 + w*32, +32).
// Key tiles of 64. Logit = c1*(qs.ks - qt*kt); softmax online; PV in bf16 MFMA (spatial),
// t-component and l in f32 lane-partials.

#define PROWB 144          // P row stride bytes (64 bf16 + 8 pad)
#define PWAVE (32 * PROWB) // per-wave P bytes

__launch_bounds__(256, 2)
__global__ void k_attn(const short* __restrict__ Qb, const short* __restrict__ Kb,
                       const short* __restrict__ VT,
                       const float* __restrict__ qt, const float* __restrict__ ktp,
                       const float* __restrict__ vtp,
                       const float* __restrict__ scalep, float* __restrict__ accum) {
  __shared__ __align__(16) char lds_k[64 * 256];    // [m][slot16] swizzled: slot ^= (m&7)
  __shared__ __align__(16) char lds_v[128 * 128];   // [d][slot16] swizzled: slot ^= (d&7)
  __shared__ __align__(16) char lds_p[4 * PWAVE];   // per-wave P (q=32 x m=64 bf16, padded)

  int t = threadIdx.x, l = t & 63, w = t >> 6;
  int lr = l & 15, lg = l >> 4;
  int h = blockIdx.y;
  int n0w = blockIdx.x * 128 + w * 32;
  float c1 = 2.0f / scalep[0];

  const short* Qh = Qb + (size_t)h * NT * DOUT;
  const short* Kh = Kb + (size_t)h * NT * DOUT;
  const short* VTh = VT + (size_t)h * DOUT * NT;
  const float* qth = qt + (size_t)h * NT;
  const float* kth = ktp + (size_t)h * NT;
  const float* vth = vtp + (size_t)h * NT;

  // Q fragments (A-layout: row = lr, k = lg*8+e) and qt*c1 per owned row
  bf16x8 aq[2][4];
#pragma unroll
  for (int qf = 0; qf < 2; ++qf)
#pragma unroll
    for (int dk = 0; dk < 4; ++dk)
      aq[qf][dk] = *(const bf16x8*)(Qh + (size_t)(n0w + 16 * qf + lr) * DOUT + dk * 32 + lg * 8);
  float qc[2][4];
#pragma unroll
  for (int qf = 0; qf < 2; ++qf)
#pragma unroll
    for (int r = 0; r < 4; ++r)
      qc[qf][r] = c1 * qth[n0w + 16 * qf + lg * 4 + r];

  f32x4 accO[2][8] = {};
  float m_run[2][4], l_run[2][4], avt_run[2][4];
#pragma unroll
  for (int qf = 0; qf < 2; ++qf)
#pragma unroll
    for (int r = 0; r < 4; ++r) {
      m_run[qf][r] = -INFINITY; l_run[qf][r] = 0.f; avt_run[qf][r] = 0.f;
    }

  for (int ktile = 0; ktile < NT / 64; ++ktile) {
    int m0 = ktile * 64;
    __syncthreads();   // previous tile fully consumed
    // stage K tile: 64 rows x 256B, source pre-swizzled so LDS slot s holds K[m][s^(m&7)]
#pragma unroll
    for (int it = 0; it < 4; ++it) {
      int c = t + it * 256;
      int m = c >> 4, s = c & 15;
      GL2LDS(Kh + (size_t)(m0 + m) * DOUT + ((s ^ (m & 7)) * 8), lds_k + c * 16);
    }
    // stage V^T tile: 128 rows x 128B
#pragma unroll
    for (int it = 0; it < 4; ++it) {
      int c = t + it * 256;
      int d = c >> 3, s = c & 7;
      GL2LDS(VTh + (size_t)d * NT + m0 + ((s ^ (d & 7)) * 8), lds_v + c * 16);
    }
    float ktv[4], vtv[4];
#pragma unroll
    for (int mf = 0; mf < 4; ++mf) {
      ktv[mf] = kth[m0 + lr + 16 * mf];
      vtv[mf] = vth[m0 + lr + 16 * mf];
    }
    __syncthreads();   // staging complete

    // ---- QK^T (spatial) ----
    f32x4 accS[2][4] = {};
#pragma unroll
    for (int dk = 0; dk < 4; ++dk) {
      bf16x8 bk[4];
#pragma unroll
      for (int mf = 0; mf < 4; ++mf) {
        int m = lr + 16 * mf;
        int slot = (4 * dk + lg) ^ (m & 7);
        bk[mf] = *(const bf16x8*)(lds_k + m * 256 + slot * 16);
      }
#pragma unroll
      for (int qf = 0; qf < 2; ++qf)
#pragma unroll
        for (int mf = 0; mf < 4; ++mf)
          accS[qf][mf] = MFMA16(aq[qf][dk], bk[mf], accS[qf][mf]);
    }

    // ---- online softmax (per-row; rows live in this lane's lg group) ----
#pragma unroll
    for (int qf = 0; qf < 2; ++qf) {
#pragma unroll
      for (int r = 0; r < 4; ++r) {
        float a[4];
#pragma unroll
        for (int mf = 0; mf < 4; ++mf)
          a[mf] = c1 * accS[qf][mf][r] - qc[qf][r] * ktv[mf];
        float mx = fmaxf(fmaxf(a[0], a[1]), fmaxf(a[2], a[3]));
        mx = fmaxf(mx, __shfl_xor(mx, 1));
        mx = fmaxf(mx, __shfl_xor(mx, 2));
        mx = fmaxf(mx, __shfl_xor(mx, 4));
        mx = fmaxf(mx, __shfl_xor(mx, 8));
        float mo = m_run[qf][r];
        float mn = fmaxf(mo, mx);
        float fsc = __expf(mo - mn);
        m_run[qf][r] = mn;
        float ps = 0.f, pv = 0.f;
        int ql = lg * 4 + r + 16 * qf;
        short* prow = (short*)(lds_p + w * PWAVE + ql * PROWB);
#pragma unroll
        for (int mf = 0; mf < 4; ++mf) {
          float p = __expf(a[mf] - mn);
          short pb = f2bf(p);
          prow[lr + 16 * mf] = pb;
          float pr = bf2f(pb);       // use the rounded value so l matches PV numerator
          ps += pr;
          pv += pr * vtv[mf];
        }
        l_run[qf][r]   = l_run[qf][r] * fsc + ps;
        avt_run[qf][r] = avt_run[qf][r] * fsc + pv;
#pragma unroll
        for (int df = 0; df < 8; ++df)
          accO[qf][df][r] *= fsc;
      }
    }

    // ---- PV (spatial, contraction over m) — P is wave-private, no barrier needed ----
#pragma unroll
    for (int ks = 0; ks < 2; ++ks) {
      bf16x8 ap[2];
#pragma unroll
      for (int qf = 0; qf < 2; ++qf)
        ap[qf] = *(const bf16x8*)(lds_p + w * PWAVE + (16 * qf + lr) * PROWB + ks * 64 + lg * 16);
      bf16x8 bv[8];
#pragma unroll
      for (int df = 0; df < 8; ++df) {
        int d = lr + 16 * df;
        int slot = (4 * ks + lg) ^ (d & 7);
        bv[df] = *(const bf16x8*)(lds_v + d * 128 + slot * 16);
      }
#pragma unroll
      for (int qf = 0; qf < 2; ++qf)
#pragma unroll
        for (int df = 0; df < 8; ++df)
          accO[qf][df] = MFMA16(ap[qf], bv[df], accO[qf][df]);
    }
  }

  // ---- epilogue: finish reductions, midpoint-norm #1, accumulate over heads ----
#pragma unroll
  for (int qf = 0; qf < 2; ++qf)
#pragma unroll
    for (int r = 0; r < 4; ++r) {
      float lv = l_run[qf][r];
      lv += __shfl_xor(lv, 1); lv += __shfl_xor(lv, 2);
      lv += __shfl_xor(lv, 4); lv += __shfl_xor(lv, 8);
      float av = avt_run[qf][r];
      av += __shfl_xor(av, 1); av += __shfl_xor(av, 2);
      av += __shfl_xor(av, 4); av += __shfl_xor(av, 8);
      float inv = 1.0f / lv;
      float at = av * inv;
      float o[8], ssq = 0.f;
#pragma unroll
      for (int df = 0; df < 8; ++df) {
        o[df] = accO[qf][df][r] * inv;
        ssq += o[df] * o[df];
      }
      ssq += __shfl_xor(ssq, 1); ssq += __shfl_xor(ssq, 2);
      ssq += __shfl_xor(ssq, 4); ssq += __shfl_xor(ssq, 8);
      float inner = ssq - at * at;
      float rden = 1.0f / sqrtf(fmaxf(fabsf(inner), 1e-8f));
      int n = n0w + 16 * qf + lg * 4 + r;
      float* arow = accum + (size_t)n * D1;
#pragma unroll
      for (int df = 0; df < 8; ++df)
        atomicAdd(arow + 1 + lr + 16 * df, o[df] * rden);
      if (lr == 0) atomicAdd(arow, at * rden);
    }
}

// ---------------- head mean + second midpoint-norm ----------------
// one wave per row

__global__ void k_final(const float* __restrict__ accum, float* __restrict__ out) {
  int r = blockIdx.x, l = threadIdx.x;
  const float* arow = accum + (size_t)r * D1;
  const float s12 = 1.0f / 12.0f;
  float va = arow[l] * s12;
  float vb = arow[64 + l] * s12;
  float vc = (l == 0) ? arow[128] * s12 : 0.0f;
  float x0 = __shfl(va, 0);
  float sp = ((l == 0) ? 0.0f : va * va) + vb * vb + vc * vc;
  sp += __shfl_xor(sp, 1);  sp += __shfl_xor(sp, 2);
  sp += __shfl_xor(sp, 4);  sp += __shfl_xor(sp, 8);
  sp += __shfl_xor(sp, 16); sp += __shfl_xor(sp, 32);
  float inner = sp - x0 * x0;
  float s = 1.0f / sqrtf(fmaxf(fabsf(inner), 1e-8f));
  out[(size_t)r * D1 + l] = va * s;
  out[(size_t)r * D1 + 64 + l] = vb * s;
  if (l == 0) out[(size_t)r * D1 + 128] = vc * s;
}

// ---------------- launch ----------------

extern "C" void kernel_launch(void* const* d_in, const int* in_sizes, int n_in,
                              void* d_out, int out_size, void* d_ws, size_t ws_size,
                              hipStream_t stream) {
  (void)in_sizes; (void)n_in; (void)out_size; (void)ws_size;
  const float* xl    = (const float*)d_in[0];
  const float* Wq    = (const float*)d_in[1];
  const float* bq    = (const float*)d_in[2];
  const float* Wk    = (const float*)d_in[3];
  const float* bk    = (const float*)d_in[4];
  const float* Wv    = (const float*)d_in[5];
  const float* bv    = (const float*)d_in[6];
  const float* scale = (const float*)d_in[7];
  // d_in[8] = bias: additive scalar inside softmax rows -> mathematically a no-op, dropped.
  float* out = (float*)d_out;

  char* ws = (char*)d_ws;
  size_t off = 0;
  auto alloc = [&](size_t b) { char* p = ws + off; off = (off + b + 255) & ~(size_t)255; return p; };
  short* xs    = (short*)alloc((size_t)NT * INS * 2);
  short* Wb    = (short*)alloc((size_t)3 * NH * DOUT * INS * 2);
  short* Qb    = (short*)alloc((size_t)NH * NT * DOUT * 2);
  short* Kb    = (short*)alloc((size_t)NH * NT * DOUT * 2);
  short* VT    = (short*)alloc((size_t)NH * DOUT * NT * 2);
  float* qt    = (float*)alloc((size_t)NH * NT * 4);
  float* kt    = (float*)alloc((size_t)NH * NT * 4);
  float* vt    = (float*)alloc((size_t)NH * NT * 4);
  float* accum = (float*)alloc((size_t)NT * D1 * 4);

  hipMemsetAsync(accum, 0, (size_t)NT * D1 * 4, stream);
  k_cvt_xs<<<NT, 256, 0, stream>>>(xl, xs);
  k_cvt_w<<<dim3(NH * DOUT * INS / 256, 3), 256, 0, stream>>>(Wq, Wk, Wv, Wb);
  k_proj<<<dim3(NT / 128, NH, 3), 256, 0, stream>>>(xs, Wb, bq, bk, bv, Qb, Kb, VT, qt, kt, vt);
  k_attn<<<dim3(NT / 128, NH), 256, 0, stream>>>(Qb, Kb, VT, qt, kt, vt, scale, accum);
  k_final<<<NT, 64, 0, stream>>>(accum, out);
}

// Round 2
// 343.387 us; speedup vs baseline: 1.2156x; 1.2156x over previous
//
#include <hip/hip_runtime.h>
#include <hip/hip_bf16.h>

#define NT   4096
#define NH   12
#define INS  256
#define DOUT 128
#define D1   129
#define PSTR 132          // partial row stride (floats): [0..127] spatial, 128: sum p*vt, 129: sum p

typedef __attribute__((ext_vector_type(8))) short bf16x8;
typedef __attribute__((ext_vector_type(4))) float f32x4;

__device__ __forceinline__ short f2bf(float f) {
  union { __hip_bfloat16 h; short s; } u;
  u.h = __float2bfloat16(f);
  return u.s;
}
__device__ __forceinline__ float bf2f(short s) {
  union { unsigned u; float f; } v;
  v.u = ((unsigned)(unsigned short)s) << 16;
  return v.f;
}

#define MFMA16(a,b,c) __builtin_amdgcn_mfma_f32_16x16x32_bf16((a),(b),(c),0,0,0)

#define GL2LDS(gp, lp) \
  __builtin_amdgcn_global_load_lds((const __attribute__((address_space(1))) unsigned*)(gp), \
                                   (__attribute__((address_space(3))) unsigned*)(lp), 16, 0, 0)

// ---------------- conversion kernels ----------------

__global__ void k_cvt_xs(const float* __restrict__ xl, short* __restrict__ xs) {
  int i = blockIdx.x * 256 + threadIdx.x;       // 0 .. NT*INS-1
  int row = i >> 8, col = i & 255;
  xs[i] = f2bf(xl[row * 257 + 1 + col]);
}

__global__ void k_cvt_w(const float* __restrict__ w0, const float* __restrict__ w1,
                        const float* __restrict__ w2, short* __restrict__ dst) {
  int i = blockIdx.x * 256 + threadIdx.x;       // 0 .. NH*DOUT*INS-1
  const float* s = blockIdx.y == 0 ? w0 : (blockIdx.y == 1 ? w1 : w2);
  dst[(size_t)blockIdx.y * (NH * DOUT * INS) + i] = f2bf(s[i]);
}

// ---------------- projection: s = xs@W^T + b ; t = sqrt(|s|^2+1) ----------------
// grid (NT/128, NH, 3), block 256 (4 waves, each 32 rows x 128 cols)

__launch_bounds__(256, 2)
__global__ void k_proj(const short* __restrict__ xs, const short* __restrict__ Wb,
                       const float* __restrict__ b0, const float* __restrict__ b1,
                       const float* __restrict__ b2,
                       short* __restrict__ Qb, short* __restrict__ Kb, short* __restrict__ VT,
                       float* __restrict__ qt, float* __restrict__ kt, float* __restrict__ vt) {
  __shared__ __align__(16) short vlds[128][144];   // V transpose staging
  int t = threadIdx.x, l = t & 63, w = t >> 6;
  int lr = l & 15, lg = l >> 4;
  int h = blockIdx.y, z = blockIdx.z;
  int n0w = blockIdx.x * 128 + w * 32;
  const short* Wh = Wb + ((size_t)z * NH + h) * DOUT * INS;
  const float* bias = z == 0 ? b0 : (z == 1 ? b1 : b2);

  f32x4 acc[2][8] = {};
#pragma unroll
  for (int dk = 0; dk < 8; ++dk) {
    bf16x8 a[2], b[8];
#pragma unroll
    for (int qf = 0; qf < 2; ++qf)
      a[qf] = *(const bf16x8*)(xs + (size_t)(n0w + 16 * qf + lr) * INS + dk * 32 + lg * 8);
#pragma unroll
    for (int cf = 0; cf < 8; ++cf)
      b[cf] = *(const bf16x8*)(Wh + (size_t)(lr + 16 * cf) * INS + dk * 32 + lg * 8);
#pragma unroll
    for (int qf = 0; qf < 2; ++qf)
#pragma unroll
      for (int cf = 0; cf < 8; ++cf)
        acc[qf][cf] = MFMA16(a[qf], b[cf], acc[qf][cf]);
  }

  float tval[2][4];
#pragma unroll
  for (int qf = 0; qf < 2; ++qf) {
    float ssq[4] = {0.f, 0.f, 0.f, 0.f};
#pragma unroll
    for (int cf = 0; cf < 8; ++cf) {
      float bv = bias[h * DOUT + lr + 16 * cf];
#pragma unroll
      for (int r = 0; r < 4; ++r) {
        acc[qf][cf][r] += bv;
        ssq[r] += acc[qf][cf][r] * acc[qf][cf][r];
      }
    }
#pragma unroll
    for (int r = 0; r < 4; ++r) {
      float s = ssq[r];
      s += __shfl_xor(s, 1); s += __shfl_xor(s, 2);
      s += __shfl_xor(s, 4); s += __shfl_xor(s, 8);
      tval[qf][r] = sqrtf(s + 1.0f);
    }
  }

  if (z < 2) {
    short* Ob = (z == 0) ? Qb : Kb;
    float* Ot = (z == 0) ? qt : kt;
#pragma unroll
    for (int qf = 0; qf < 2; ++qf)
#pragma unroll
      for (int r = 0; r < 4; ++r) {
        int n = n0w + 16 * qf + lg * 4 + r;
#pragma unroll
        for (int cf = 0; cf < 8; ++cf)
          Ob[((size_t)h * NT + n) * DOUT + lr + 16 * cf] = f2bf(acc[qf][cf][r]);
        if (lr == 0) Ot[(size_t)h * NT + n] = tval[qf][r];
      }
  } else {
    // V: write transposed (H, DOUT, NT) via LDS for coalescing
#pragma unroll
    for (int qf = 0; qf < 2; ++qf)
#pragma unroll
      for (int cf = 0; cf < 8; ++cf)
#pragma unroll
        for (int r = 0; r < 4; ++r) {
          int nl = w * 32 + 16 * qf + lg * 4 + r;
          vlds[lr + 16 * cf][nl] = f2bf(acc[qf][cf][r]);
        }
#pragma unroll
    for (int qf = 0; qf < 2; ++qf)
#pragma unroll
      for (int r = 0; r < 4; ++r) {
        int n = n0w + 16 * qf + lg * 4 + r;
        if (lr == 0) vt[(size_t)h * NT + n] = tval[qf][r];
      }
    __syncthreads();
    int d = t >> 1, half = t & 1;
    const short* src = &vlds[d][half * 64];
    short* dst = VT + ((size_t)h * DOUT + d) * NT + blockIdx.x * 128 + half * 64;
#pragma unroll
    for (int j = 0; j < 8; ++j)
      *(bf16x8*)(dst + j * 8) = *(const bf16x8*)(src + j * 8);
  }
}

// ---------------- flash attention (max-free softmax, split-KV) ----------------
// Logits are provably <= ~0 (Lorentz inner product <= -1), so p = exp(logit) needs
// no running max -> partial sums are linear -> split keys 2-way for occupancy.
// grid (NT/128, NH, 2), block 256. Wave w owns q-rows [blk*128 + w*32, +32);
// z selects key half [z*2048, z*2048+2048). Unnormalized partials atomicAdd'd
// into part[(h*NT+n)*PSTR + {d | 128:pvt | 129:psum}].

#define PROWB 144          // P row stride bytes (64 bf16 + 8 pad)
#define PWAVE (32 * PROWB) // per-wave P bytes

__launch_bounds__(256, 2)
__global__ void k_attn(const short* __restrict__ Qb, const short* __restrict__ Kb,
                       const short* __restrict__ VT,
                       const float* __restrict__ qt, const float* __restrict__ ktp,
                       const float* __restrict__ vtp,
                       const float* __restrict__ scalep, float* __restrict__ part) {
  __shared__ __align__(16) char lds_k[64 * 256];    // [m][slot16] swizzled: slot ^= (m&7)
  __shared__ __align__(16) char lds_v[128 * 128];   // [d][slot16] swizzled: slot ^= (d&7)
  __shared__ __align__(16) char lds_p[4 * PWAVE];   // per-wave P (q=32 x m=64 bf16, padded)

  int t = threadIdx.x, l = t & 63, w = t >> 6;
  int lr = l & 15, lg = l >> 4;
  int h = blockIdx.y, z = blockIdx.z;
  int n0w = blockIdx.x * 128 + w * 32;
  float c1 = 2.0f / scalep[0];

  const short* Qh = Qb + (size_t)h * NT * DOUT;
  const short* Kh = Kb + (size_t)h * NT * DOUT;
  const short* VTh = VT + (size_t)h * DOUT * NT;
  const float* qth = qt + (size_t)h * NT;
  const float* kth = ktp + (size_t)h * NT;
  const float* vth = vtp + (size_t)h * NT;

  // Q fragments (A-layout: row = lr, k = lg*8+e) and qt*c1 per owned row
  bf16x8 aq[2][4];
#pragma unroll
  for (int qf = 0; qf < 2; ++qf)
#pragma unroll
    for (int dk = 0; dk < 4; ++dk)
      aq[qf][dk] = *(const bf16x8*)(Qh + (size_t)(n0w + 16 * qf + lr) * DOUT + dk * 32 + lg * 8);
  float qc[2][4];
#pragma unroll
  for (int qf = 0; qf < 2; ++qf)
#pragma unroll
    for (int r = 0; r < 4; ++r)
      qc[qf][r] = c1 * qth[n0w + 16 * qf + lg * 4 + r];

  f32x4 accO[2][8] = {};
  float l_run[2][4] = {}, avt_run[2][4] = {};

  for (int ktile = 0; ktile < NT / 128; ++ktile) {   // 32 tiles of 64 keys (half the keys)
    int m0 = z * (NT / 2) + ktile * 64;
    __syncthreads();   // previous tile fully consumed
    // stage K tile: 64 rows x 256B, source pre-swizzled so LDS slot s holds K[m][s^(m&7)]
#pragma unroll
    for (int it = 0; it < 4; ++it) {
      int c = t + it * 256;
      int m = c >> 4, s = c & 15;
      GL2LDS(Kh + (size_t)(m0 + m) * DOUT + ((s ^ (m & 7)) * 8), lds_k + c * 16);
    }
    // stage V^T tile: 128 rows x 128B
#pragma unroll
    for (int it = 0; it < 4; ++it) {
      int c = t + it * 256;
      int d = c >> 3, s = c & 7;
      GL2LDS(VTh + (size_t)d * NT + m0 + ((s ^ (d & 7)) * 8), lds_v + c * 16);
    }
    float ktv[4], vtv[4];
#pragma unroll
    for (int mf = 0; mf < 4; ++mf) {
      ktv[mf] = kth[m0 + lr + 16 * mf];
      vtv[mf] = vth[m0 + lr + 16 * mf];
    }
    __syncthreads();   // staging complete

    // ---- QK^T (spatial) ----
    f32x4 accS[2][4] = {};
#pragma unroll
    for (int dk = 0; dk < 4; ++dk) {
      bf16x8 bk[4];
#pragma unroll
      for (int mf = 0; mf < 4; ++mf) {
        int m = lr + 16 * mf;
        int slot = (4 * dk + lg) ^ (m & 7);
        bk[mf] = *(const bf16x8*)(lds_k + m * 256 + slot * 16);
      }
#pragma unroll
      for (int qf = 0; qf < 2; ++qf)
#pragma unroll
        for (int mf = 0; mf < 4; ++mf)
          accS[qf][mf] = MFMA16(aq[qf][dk], bk[mf], accS[qf][mf]);
    }

    // ---- max-free softmax: p = exp(c1*qs.ks - c1*qt*kt), provably <= ~1 ----
#pragma unroll
    for (int qf = 0; qf < 2; ++qf) {
#pragma unroll
      for (int r = 0; r < 4; ++r) {
        int ql = lg * 4 + r + 16 * qf;
        short* prow = (short*)(lds_p + w * PWAVE + ql * PROWB);
        float ps = 0.f, pv = 0.f;
#pragma unroll
        for (int mf = 0; mf < 4; ++mf) {
          float a = fmaf(-qc[qf][r], ktv[mf], c1 * accS[qf][mf][r]);
          float p = __expf(a);
          short pb = f2bf(p);
          prow[lr + 16 * mf] = pb;
          float pr = bf2f(pb);       // rounded value so denominator matches PV numerator
          ps += pr;
          pv += pr * vtv[mf];
        }
        l_run[qf][r]   += ps;
        avt_run[qf][r] += pv;
      }
    }

    // ---- PV (spatial, contraction over m) — P is wave-private, no barrier needed ----
#pragma unroll
    for (int ks = 0; ks < 2; ++ks) {
      bf16x8 ap[2];
#pragma unroll
      for (int qf = 0; qf < 2; ++qf)
        ap[qf] = *(const bf16x8*)(lds_p + w * PWAVE + (16 * qf + lr) * PROWB + ks * 64 + lg * 16);
      bf16x8 bv[8];
#pragma unroll
      for (int df = 0; df < 8; ++df) {
        int d = lr + 16 * df;
        int slot = (4 * ks + lg) ^ (d & 7);
        bv[df] = *(const bf16x8*)(lds_v + d * 128 + slot * 16);
      }
#pragma unroll
      for (int qf = 0; qf < 2; ++qf)
#pragma unroll
        for (int df = 0; df < 8; ++df)
          accO[qf][df] = MFMA16(ap[qf], bv[df], accO[qf][df]);
    }
  }

  // ---- epilogue: reduce lane-partials, accumulate unnormalized partials ----
#pragma unroll
  for (int qf = 0; qf < 2; ++qf)
#pragma unroll
    for (int r = 0; r < 4; ++r) {
      float lv = l_run[qf][r];
      lv += __shfl_xor(lv, 1); lv += __shfl_xor(lv, 2);
      lv += __shfl_xor(lv, 4); lv += __shfl_xor(lv, 8);
      float av = avt_run[qf][r];
      av += __shfl_xor(av, 1); av += __shfl_xor(av, 2);
      av += __shfl_xor(av, 4); av += __shfl_xor(av, 8);
      int n = n0w + 16 * qf + lg * 4 + r;
      float* base = part + ((size_t)h * NT + n) * PSTR;
#pragma unroll
      for (int df = 0; df < 8; ++df)
        atomicAdd(base + lr + 16 * df, accO[qf][df][r]);
      if (lr == 0) { atomicAdd(base + 128, av); atomicAdd(base + 129, lv); }
    }
}

// ---------------- combine: normalize, midpoint-norm #1, head mean, midpoint-norm #2 ----------------
// block 256 = 4 waves, wave w handles row n = blockIdx.x*4 + w

__global__ void k_comb(const float* __restrict__ part, float* __restrict__ out) {
  int l = threadIdx.x & 63, w = threadIdx.x >> 6;
  int n = blockIdx.x * 4 + w;
  float acc_lo = 0.f, acc_hi = 0.f, acc_t = 0.f;
#pragma unroll
  for (int h = 0; h < NH; ++h) {
    const float* p = part + ((size_t)h * NT + n) * PSTR;
    float x = p[l], y = p[64 + l], pvt = p[128], pl = p[129];
    float inv = 1.0f / pl;
    float olo = x * inv, ohi = y * inv, at = pvt * inv;
    float sp = olo * olo + ohi * ohi;
    sp += __shfl_xor(sp, 1);  sp += __shfl_xor(sp, 2);
    sp += __shfl_xor(sp, 4);  sp += __shfl_xor(sp, 8);
    sp += __shfl_xor(sp, 16); sp += __shfl_xor(sp, 32);
    float inner = sp - at * at;
    float rd = 1.0f / sqrtf(fmaxf(fabsf(inner), 1e-8f));
    acc_lo += olo * rd; acc_hi += ohi * rd; acc_t += at * rd;
  }
  const float m = 1.0f / (float)NH;
  float vlo = acc_lo * m, vhi = acc_hi * m, vt = acc_t * m;
  float sp = vlo * vlo + vhi * vhi;
  sp += __shfl_xor(sp, 1);  sp += __shfl_xor(sp, 2);
  sp += __shfl_xor(sp, 4);  sp += __shfl_xor(sp, 8);
  sp += __shfl_xor(sp, 16); sp += __shfl_xor(sp, 32);
  float inner = sp - vt * vt;
  float rd = 1.0f / sqrtf(fmaxf(fabsf(inner), 1e-8f));
  float* orow = out + (size_t)n * D1;
  orow[1 + l] = vlo * rd;
  orow[65 + l] = vhi * rd;
  if (l == 0) orow[0] = vt * rd;
}

// ---------------- launch ----------------

extern "C" void kernel_launch(void* const* d_in, const int* in_sizes, int n_in,
                              void* d_out, int out_size, void* d_ws, size_t ws_size,
                              hipStream_t stream) {
  (void)in_sizes; (void)n_in; (void)out_size; (void)ws_size;
  const float* xl    = (const float*)d_in[0];
  const float* Wq    = (const float*)d_in[1];
  const float* bq    = (const float*)d_in[2];
  const float* Wk    = (const float*)d_in[3];
  const float* bk    = (const float*)d_in[4];
  const float* Wv    = (const float*)d_in[5];
  const float* bv    = (const float*)d_in[6];
  const float* scale = (const float*)d_in[7];
  // d_in[8] = bias: additive scalar inside softmax rows -> mathematically a no-op, dropped.
  float* out = (float*)d_out;

  char* ws = (char*)d_ws;
  size_t off = 0;
  auto alloc = [&](size_t b) { char* p = ws + off; off = (off + b + 255) & ~(size_t)255; return p; };
  short* xs    = (short*)alloc((size_t)NT * INS * 2);
  short* Wb    = (short*)alloc((size_t)3 * NH * DOUT * INS * 2);
  short* Qb    = (short*)alloc((size_t)NH * NT * DOUT * 2);
  short* Kb    = (short*)alloc((size_t)NH * NT * DOUT * 2);
  short* VT    = (short*)alloc((size_t)NH * DOUT * NT * 2);
  float* qt    = (float*)alloc((size_t)NH * NT * 4);
  float* kt    = (float*)alloc((size_t)NH * NT * 4);
  float* vt    = (float*)alloc((size_t)NH * NT * 4);
  float* part  = (float*)alloc((size_t)NH * NT * PSTR * 4);

  hipMemsetAsync(part, 0, (size_t)NH * NT * PSTR * 4, stream);
  k_cvt_xs<<<NT, 256, 0, stream>>>(xl, xs);
  k_cvt_w<<<dim3(NH * DOUT * INS / 256, 3), 256, 0, stream>>>(Wq, Wk, Wv, Wb);
  k_proj<<<dim3(NT / 128, NH, 3), 256, 0, stream>>>(xs, Wb, bq, bk, bv, Qb, Kb, VT, qt, kt, vt);
  k_attn<<<dim3(NT / 128, NH, 2), 256, 0, stream>>>(Qb, Kb, VT, qt, kt, vt, scale, part);
  k_comb<<<NT / 4, 256, 0, stream>>>(part, out);
}

// Round 3
// 323.173 us; speedup vs baseline: 1.2916x; 1.0625x over previous
//
#include <hip/hip_runtime.h>
#include <hip/hip_bf16.h>

#define NT   4096
#define NH   12
#define INS  256
#define DOUT 128
#define D1   129
#define PSTR 132          // partial row stride (floats): [0..127] spatial (sum p*vs), 128: sum p*vt

typedef __attribute__((ext_vector_type(8))) short bf16x8;
typedef __attribute__((ext_vector_type(4))) float f32x4;

__device__ __forceinline__ short f2bf(float f) {
  union { __hip_bfloat16 h; short s; } u;
  u.h = __float2bfloat16(f);
  return u.s;
}
__device__ __forceinline__ float bf2f(short s) {
  union { unsigned u; float f; } v;
  v.u = ((unsigned)(unsigned short)s) << 16;
  return v.f;
}

#define MFMA16(a,b,c) __builtin_amdgcn_mfma_f32_16x16x32_bf16((a),(b),(c),0,0,0)

#define GL2LDS(gp, lp) \
  __builtin_amdgcn_global_load_lds((const __attribute__((address_space(1))) unsigned*)(gp), \
                                   (__attribute__((address_space(3))) unsigned*)(lp), 16, 0, 0)

// ---------------- conversion kernels ----------------

__global__ void k_cvt_xs(const float* __restrict__ xl, short* __restrict__ xs) {
  int i = blockIdx.x * 256 + threadIdx.x;       // 0 .. NT*INS-1
  int row = i >> 8, col = i & 255;
  xs[i] = f2bf(xl[row * 257 + 1 + col]);
}

__global__ void k_cvt_w(const float* __restrict__ w0, const float* __restrict__ w1,
                        const float* __restrict__ w2, short* __restrict__ dst) {
  int i = blockIdx.x * 256 + threadIdx.x;       // 0 .. NH*DOUT*INS-1
  const float* s = blockIdx.y == 0 ? w0 : (blockIdx.y == 1 ? w1 : w2);
  dst[(size_t)blockIdx.y * (NH * DOUT * INS) + i] = f2bf(s[i]);
}

// ---------------- projection: s = xs@W^T + b ; t = sqrt(|s|^2+1) ----------------
// grid (NT/128, NH, 3), block 256 (4 waves, each 32 rows x 128 cols)
// Q (z==0) is pre-scaled by c2 = 2*log2(e)/scale so attention does p = exp2(qs.ks - qt*kt).

__launch_bounds__(256, 2)
__global__ void k_proj(const short* __restrict__ xs, const short* __restrict__ Wb,
                       const float* __restrict__ b0, const float* __restrict__ b1,
                       const float* __restrict__ b2, const float* __restrict__ scalep,
                       short* __restrict__ Qb, short* __restrict__ Kb, short* __restrict__ VT,
                       float* __restrict__ qt, float* __restrict__ kt, float* __restrict__ vt) {
  __shared__ __align__(16) short vlds[128][144];   // V transpose staging
  int t = threadIdx.x, l = t & 63, w = t >> 6;
  int lr = l & 15, lg = l >> 4;
  int h = blockIdx.y, z = blockIdx.z;
  int n0w = blockIdx.x * 128 + w * 32;
  const short* Wh = Wb + ((size_t)z * NH + h) * DOUT * INS;
  const float* bias = z == 0 ? b0 : (z == 1 ? b1 : b2);

  f32x4 acc[2][8] = {};
#pragma unroll
  for (int dk = 0; dk < 8; ++dk) {
    bf16x8 a[2], b[8];
#pragma unroll
    for (int qf = 0; qf < 2; ++qf)
      a[qf] = *(const bf16x8*)(xs + (size_t)(n0w + 16 * qf + lr) * INS + dk * 32 + lg * 8);
#pragma unroll
    for (int cf = 0; cf < 8; ++cf)
      b[cf] = *(const bf16x8*)(Wh + (size_t)(lr + 16 * cf) * INS + dk * 32 + lg * 8);
#pragma unroll
    for (int qf = 0; qf < 2; ++qf)
#pragma unroll
      for (int cf = 0; cf < 8; ++cf)
        acc[qf][cf] = MFMA16(a[qf], b[cf], acc[qf][cf]);
  }

  float tval[2][4];
#pragma unroll
  for (int qf = 0; qf < 2; ++qf) {
    float ssq[4] = {0.f, 0.f, 0.f, 0.f};
#pragma unroll
    for (int cf = 0; cf < 8; ++cf) {
      float bv = bias[h * DOUT + lr + 16 * cf];
#pragma unroll
      for (int r = 0; r < 4; ++r) {
        acc[qf][cf][r] += bv;
        ssq[r] += acc[qf][cf][r] * acc[qf][cf][r];
      }
    }
#pragma unroll
    for (int r = 0; r < 4; ++r) {
      float s = ssq[r];
      s += __shfl_xor(s, 1); s += __shfl_xor(s, 2);
      s += __shfl_xor(s, 4); s += __shfl_xor(s, 8);
      tval[qf][r] = sqrtf(s + 1.0f);
    }
  }

  if (z < 2) {
    float f = (z == 0) ? (2.0f * 1.442695040888963f / scalep[0]) : 1.0f;
    short* Ob = (z == 0) ? Qb : Kb;
    float* Ot = (z == 0) ? qt : kt;
#pragma unroll
    for (int qf = 0; qf < 2; ++qf)
#pragma unroll
      for (int r = 0; r < 4; ++r) {
        int n = n0w + 16 * qf + lg * 4 + r;
#pragma unroll
        for (int cf = 0; cf < 8; ++cf)
          Ob[((size_t)h * NT + n) * DOUT + lr + 16 * cf] = f2bf(acc[qf][cf][r] * f);
        if (lr == 0) Ot[(size_t)h * NT + n] = tval[qf][r] * f;
      }
  } else {
    // V: write transposed (H, DOUT, NT) via LDS for coalescing
#pragma unroll
    for (int qf = 0; qf < 2; ++qf)
#pragma unroll
      for (int cf = 0; cf < 8; ++cf)
#pragma unroll
        for (int r = 0; r < 4; ++r) {
          int nl = w * 32 + 16 * qf + lg * 4 + r;
          vlds[lr + 16 * cf][nl] = f2bf(acc[qf][cf][r]);
        }
#pragma unroll
    for (int qf = 0; qf < 2; ++qf)
#pragma unroll
      for (int r = 0; r < 4; ++r) {
        int n = n0w + 16 * qf + lg * 4 + r;
        if (lr == 0) vt[(size_t)h * NT + n] = tval[qf][r];
      }
    __syncthreads();
    int d = t >> 1, half = t & 1;
    const short* src = &vlds[d][half * 64];
    short* dst = VT + ((size_t)h * DOUT + d) * NT + blockIdx.x * 128 + half * 64;
#pragma unroll
    for (int j = 0; j < 8; ++j)
      *(bf16x8*)(dst + j * 8) = *(const bf16x8*)(src + j * 8);
  }
}

// ---------------- flash attention (max-free softmax, split-KV, split-phase pipeline) ----------------
// Logits <= ~0 (Lorentz inner <= -1) -> no running max. midpoint_norm is scale-invariant
// -> softmax denominator cancels -> no l accumulation at all, and partials are linear
// (split keys 2-way). Pipeline: K_t staged during prev iter's PV phase; V_t staged during
// this iter's QK^T phase -> each barrier's vmcnt(0) drain waits on loads issued a full
// compute phase earlier (T14) instead of immediately before.
// grid (NT/128, NH, 2), block 256. part[(h*NT+n)*PSTR + {d | 128: sum p*vt}] (unnormalized).

#define PROWB 144          // P row stride bytes (64 bf16 + 8 pad)
#define PWAVE (32 * PROWB) // per-wave P bytes

__launch_bounds__(256, 2)
__global__ void k_attn(const short* __restrict__ Qb, const short* __restrict__ Kb,
                       const short* __restrict__ VT,
                       const float* __restrict__ qt, const float* __restrict__ ktp,
                       const float* __restrict__ vtp, float* __restrict__ part) {
  __shared__ __align__(16) char lds_k[64 * 256];    // [m][slot16] swizzled: slot ^= (m&7)
  __shared__ __align__(16) char lds_v[128 * 128];   // [d][slot16] swizzled: slot ^= (d&7)
  __shared__ __align__(16) char lds_p[4 * PWAVE];   // per-wave P (q=32 x m=64 bf16, padded)

  int t = threadIdx.x, l = t & 63, w = t >> 6;
  int lr = l & 15, lg = l >> 4;
  int h = blockIdx.y, z = blockIdx.z;
  int n0w = blockIdx.x * 128 + w * 32;

  const short* Qh = Qb + (size_t)h * NT * DOUT;
  const short* Kh = Kb + (size_t)h * NT * DOUT;
  const short* VTh = VT + (size_t)h * DOUT * NT;
  const float* qth = qt + (size_t)h * NT;
  const float* kth = ktp + (size_t)h * NT;
  const float* vth = vtp + (size_t)h * NT;

  // Q fragments (pre-scaled by c2 at projection) and qc2 = c2*qt per owned row
  bf16x8 aq[2][4];
#pragma unroll
  for (int qf = 0; qf < 2; ++qf)
#pragma unroll
    for (int dk = 0; dk < 4; ++dk)
      aq[qf][dk] = *(const bf16x8*)(Qh + (size_t)(n0w + 16 * qf + lr) * DOUT + dk * 32 + lg * 8);
  float qc2[2][4];
#pragma unroll
  for (int qf = 0; qf < 2; ++qf)
#pragma unroll
    for (int r = 0; r < 4; ++r)
      qc2[qf][r] = qth[n0w + 16 * qf + lg * 4 + r];

  f32x4 accO[2][8] = {};
  float avt_run[2][4] = {};

  // per-thread staging coordinates (constant across tiles)
  int kc_m = t >> 2, kc_s = (t & 3);                 // with it-offset below
  (void)kc_m; (void)kc_s;

  // prologue: issue K tile 0 (source pre-swizzled, LDS linear)
  {
    int m0 = z * (NT / 2);
#pragma unroll
    for (int it = 0; it < 4; ++it) {
      int c = t + it * 256;
      int m = c >> 4, s = c & 15;
      GL2LDS(Kh + (size_t)(m0 + m) * DOUT + ((s ^ (m & 7)) * 8), lds_k + c * 16);
    }
  }

  for (int ktile = 0; ktile < NT / 128; ++ktile) {   // 32 tiles of 64 keys (half the keys)
    int m0 = z * (NT / 2) + ktile * 64;
    __syncthreads();   // drains K_t into LDS; lds_v free (prev PV done)

    // issue V_t (consumed after mid-barrier, latency hidden under QK^T+softmax)
#pragma unroll
    for (int it = 0; it < 4; ++it) {
      int c = t + it * 256;
      int d = c >> 3, s = c & 7;
      GL2LDS(VTh + (size_t)d * NT + m0 + ((s ^ (d & 7)) * 8), lds_v + c * 16);
    }
    float ktv[4], vtv[4];
#pragma unroll
    for (int mf = 0; mf < 4; ++mf) {
      ktv[mf] = kth[m0 + lr + 16 * mf];
      vtv[mf] = vth[m0 + lr + 16 * mf];
    }

    // ---- QK^T (spatial, Q pre-scaled) ----
    f32x4 accS[2][4] = {};
#pragma unroll
    for (int dk = 0; dk < 4; ++dk) {
      bf16x8 bk[4];
#pragma unroll
      for (int mf = 0; mf < 4; ++mf) {
        int m = lr + 16 * mf;
        int slot = (4 * dk + lg) ^ (m & 7);
        bk[mf] = *(const bf16x8*)(lds_k + m * 256 + slot * 16);
      }
#pragma unroll
      for (int qf = 0; qf < 2; ++qf)
#pragma unroll
        for (int mf = 0; mf < 4; ++mf)
          accS[qf][mf] = MFMA16(aq[qf][dk], bk[mf], accS[qf][mf]);
    }

    // ---- max-free softmax: p = exp2(qs.ks - qt*kt) (both pre-scaled by c2) ----
#pragma unroll
    for (int qf = 0; qf < 2; ++qf) {
#pragma unroll
      for (int r = 0; r < 4; ++r) {
        int ql = lg * 4 + r + 16 * qf;
        short* prow = (short*)(lds_p + w * PWAVE + ql * PROWB);
        float pv = 0.f;
#pragma unroll
        for (int mf = 0; mf < 4; ++mf) {
          float a2 = fmaf(-qc2[qf][r], ktv[mf], accS[qf][mf][r]);
          float p;
          asm("v_exp_f32 %0, %1" : "=v"(p) : "v"(a2));
          short pb = f2bf(p);
          prow[lr + 16 * mf] = pb;
          pv = fmaf(bf2f(pb), vtv[mf], pv);  // rounded p so t-component matches PV numerator
        }
        avt_run[qf][r] += pv;
      }
    }

    __syncthreads();   // drains V_t; all waves past QK^T (lds_k free)

    // issue K_{t+1} (consumed after next loop-top barrier, latency hidden under PV)
    if (ktile + 1 < NT / 128) {
      int m1 = m0 + 64;
#pragma unroll
      for (int it = 0; it < 4; ++it) {
        int c = t + it * 256;
        int m = c >> 4, s = c & 15;
        GL2LDS(Kh + (size_t)(m1 + m) * DOUT + ((s ^ (m & 7)) * 8), lds_k + c * 16);
      }
    }

    // ---- PV (spatial, contraction over m) — P is wave-private ----
#pragma unroll
    for (int ks = 0; ks < 2; ++ks) {
      bf16x8 ap[2];
#pragma unroll
      for (int qf = 0; qf < 2; ++qf)
        ap[qf] = *(const bf16x8*)(lds_p + w * PWAVE + (16 * qf + lr) * PROWB + ks * 64 + lg * 16);
      bf16x8 bv[8];
#pragma unroll
      for (int df = 0; df < 8; ++df) {
        int d = lr + 16 * df;
        int slot = (4 * ks + lg) ^ (d & 7);
        bv[df] = *(const bf16x8*)(lds_v + d * 128 + slot * 16);
      }
#pragma unroll
      for (int qf = 0; qf < 2; ++qf)
#pragma unroll
        for (int df = 0; df < 8; ++df)
          accO[qf][df] = MFMA16(ap[qf], bv[df], accO[qf][df]);
    }
  }

  // ---- epilogue: reduce avt lane-partials, accumulate unnormalized partials ----
#pragma unroll
  for (int qf = 0; qf < 2; ++qf)
#pragma unroll
    for (int r = 0; r < 4; ++r) {
      float av = avt_run[qf][r];
      av += __shfl_xor(av, 1); av += __shfl_xor(av, 2);
      av += __shfl_xor(av, 4); av += __shfl_xor(av, 8);
      int n = n0w + 16 * qf + lg * 4 + r;
      float* base = part + ((size_t)h * NT + n) * PSTR;
#pragma unroll
      for (int df = 0; df < 8; ++df)
        atomicAdd(base + lr + 16 * df, accO[qf][df][r]);
      if (lr == 0) atomicAdd(base + 128, av);
    }
}

// ---------------- combine: midpoint-norm #1 per head, head sum, midpoint-norm #2 ----------------
// midpoint_norm is scale-invariant -> no softmax denominator, no 1/NH needed.
// block 256 = 4 waves, wave w handles row n = blockIdx.x*4 + w

__global__ void k_comb(const float* __restrict__ part, float* __restrict__ out) {
  int l = threadIdx.x & 63, w = threadIdx.x >> 6;
  int n = blockIdx.x * 4 + w;
  float acc_lo = 0.f, acc_hi = 0.f, acc_t = 0.f;
#pragma unroll
  for (int h = 0; h < NH; ++h) {
    const float* p = part + ((size_t)h * NT + n) * PSTR;
    float x = p[l], y = p[64 + l], at = p[128];
    float sp = x * x + y * y;
    sp += __shfl_xor(sp, 1);  sp += __shfl_xor(sp, 2);
    sp += __shfl_xor(sp, 4);  sp += __shfl_xor(sp, 8);
    sp += __shfl_xor(sp, 16); sp += __shfl_xor(sp, 32);
    float inner = sp - at * at;
    float rd = 1.0f / sqrtf(fmaxf(fabsf(inner), 1e-8f));
    acc_lo += x * rd; acc_hi += y * rd; acc_t += at * rd;
  }
  float sp = acc_lo * acc_lo + acc_hi * acc_hi;
  sp += __shfl_xor(sp, 1);  sp += __shfl_xor(sp, 2);
  sp += __shfl_xor(sp, 4);  sp += __shfl_xor(sp, 8);
  sp += __shfl_xor(sp, 16); sp += __shfl_xor(sp, 32);
  float inner = sp - acc_t * acc_t;
  float rd = 1.0f / sqrtf(fmaxf(fabsf(inner), 1e-8f));
  float* orow = out + (size_t)n * D1;
  orow[1 + l] = acc_lo * rd;
  orow[65 + l] = acc_hi * rd;
  if (l == 0) orow[0] = acc_t * rd;
}

// ---------------- launch ----------------

extern "C" void kernel_launch(void* const* d_in, const int* in_sizes, int n_in,
                              void* d_out, int out_size, void* d_ws, size_t ws_size,
                              hipStream_t stream) {
  (void)in_sizes; (void)n_in; (void)out_size; (void)ws_size;
  const float* xl    = (const float*)d_in[0];
  const float* Wq    = (const float*)d_in[1];
  const float* bq    = (const float*)d_in[2];
  const float* Wk    = (const float*)d_in[3];
  const float* bk    = (const float*)d_in[4];
  const float* Wv    = (const float*)d_in[5];
  const float* bv    = (const float*)d_in[6];
  const float* scale = (const float*)d_in[7];
  // d_in[8] = bias: additive scalar inside softmax rows -> no-op (softmax shift-invariant
  // + midpoint_norm scale-invariant), dropped.
  float* out = (float*)d_out;

  char* ws = (char*)d_ws;
  size_t off = 0;
  auto alloc = [&](size_t b) { char* p = ws + off; off = (off + b + 255) & ~(size_t)255; return p; };
  short* xs    = (short*)alloc((size_t)NT * INS * 2);
  short* Wb    = (short*)alloc((size_t)3 * NH * DOUT * INS * 2);
  short* Qb    = (short*)alloc((size_t)NH * NT * DOUT * 2);
  short* Kb    = (short*)alloc((size_t)NH * NT * DOUT * 2);
  short* VT    = (short*)alloc((size_t)NH * DOUT * NT * 2);
  float* qt    = (float*)alloc((size_t)NH * NT * 4);
  float* kt    = (float*)alloc((size_t)NH * NT * 4);
  float* vt    = (float*)alloc((size_t)NH * NT * 4);
  float* part  = (float*)alloc((size_t)NH * NT * PSTR * 4);

  hipMemsetAsync(part, 0, (size_t)NH * NT * PSTR * 4, stream);
  k_cvt_xs<<<NT, 256, 0, stream>>>(xl, xs);
  k_cvt_w<<<dim3(NH * DOUT * INS / 256, 3), 256, 0, stream>>>(Wq, Wk, Wv, Wb);
  k_proj<<<dim3(NT / 128, NH, 3), 256, 0, stream>>>(xs, Wb, bq, bk, bv, scale, Qb, Kb, VT, qt, kt, vt);
  k_attn<<<dim3(NT / 128, NH, 2), 256, 0, stream>>>(Qb, Kb, VT, qt, kt, vt, part);
  k_comb<<<NT / 4, 256, 0, stream>>>(part, out);
}